// Round 6
// baseline (478.299 us; speedup 1.0000x reference)
//
#include <hip/hip_runtime.h>

// Batched 8x8 iDCT: out = M^T * img * M + 128
//   M[i][j] = 0.5 * a[i] * cos((2j+1)*i*pi/16)
//   a[i]    = alpha[i*8+1]       (alpha = outer(a,a), a[1]==1)
//   cos term = dct[i*512 + j*8]  (dct_tensor[i,0,j,0]; cos(0)==1)
//
// Design F: persistent row-per-lane + double-buffered LDS + 1-deep prefetch.
//   - 8 lanes per block, lane owns one row: loads/stores 2x dwordx4, 32B/lane,
//     WG covers float4 [tile*512 .. tile*512+511] linearly (thread t -> 2t,2t+1)
//   - next tile's loads issued before current tile's compute -> HBM always busy
//   - M broadcast to SGPRs via v_readlane (no scalar-FP path on CDNA) -> low VGPR
//   - P staged in LDS, stride 17 float4/block -> even bank groups, no conflicts
//   - double-buffered P + single barrier/tile (barrier(i+1) orders read(i) vs write(i+2))
//   - non-temporal output stores (native ext_vector_type for the builtin)

#define WG      256
#define BPW     (WG / 8)       // 32 blocks per tile
#define STRIDE4 17             // float4 stride per block in LDS
#define MAXWG   2048           // persistent grid (8 WG/CU * 256 CU)

typedef float fx4 __attribute__((ext_vector_type(4)));

__global__ __launch_bounds__(WG, 8) void dct8x8_kernel(
    const float* __restrict__ image,
    const float* __restrict__ alpha,
    const float* __restrict__ dct,
    float* __restrict__ out,
    int nblocks)
{
    __shared__ float4 lds4[2 * BPW * STRIDE4];   // 2 x 8.5KB

    const int t = threadIdx.x;
    const int b = t >> 3;          // local block 0..31
    const int r = t & 7;           // my row
    const int lane = t & 63;

    // ---- M -> SGPRs: compute one element per lane, readlane-broadcast ----
    float mv;
    {
        const int i = lane >> 3, j = lane & 7;
        mv = 0.5f * alpha[i * 8 + 1] * dct[i * 512 + j * 8];
    }
    float M[64];
#pragma unroll
    for (int k = 0; k < 64; ++k)
        M[k] = __int_as_float(__builtin_amdgcn_readlane(__float_as_int(mv), k));

    // ---- stage-2 weights M[x][r] (runtime r) stay per-lane in VGPRs ----
    float mu[8];
#pragma unroll
    for (int x = 0; x < 8; ++x)
        mu[x] = 0.5f * alpha[x * 8 + 1] * dct[x * 512 + r * 8];

    const long long ntiles = ((long long)nblocks + BPW - 1) / BPW;
    const float4* __restrict__ in4 = (const float4*)image;
    fx4* __restrict__ o4 = (fx4*)out;

    long long tile = blockIdx.x;
    if (tile >= ntiles) return;

    // ---- prologue: load tile0 ----
    float4 clo = make_float4(0.f, 0.f, 0.f, 0.f), chi = clo;
    if (tile * BPW + b < nblocks) {
        const size_t p = (size_t)tile * (BPW * 16) + 2 * t;
        clo = in4[p]; chi = in4[p + 1];
    }

    int bufsel = 0;
    while (tile < ntiles) {
        // ---- issue next tile's loads (in flight across compute + barrier) ----
        const long long nxt = tile + gridDim.x;
        float4 nlo = make_float4(0.f, 0.f, 0.f, 0.f), nhi = nlo;
        if (nxt < ntiles && nxt * BPW + b < nblocks) {
            const size_t p = (size_t)nxt * (BPW * 16) + 2 * t;
            nlo = in4[p]; nhi = in4[p + 1];
        }

        // ---- stage 1: P[v] = sum_y row[y] * M[y][v] ----
        float P[8];
        {
            const float row[8] = {clo.x, clo.y, clo.z, clo.w,
                                  chi.x, chi.y, chi.z, chi.w};
#pragma unroll
            for (int v = 0; v < 8; ++v) {
                float s = 0.0f;
#pragma unroll
                for (int y = 0; y < 8; ++y)
                    s = fmaf(row[y], M[y * 8 + v], s);
                P[v] = s;
            }
        }

        // ---- stage P to LDS (double-buffered) ----
        float4* buf = &lds4[bufsel * (BPW * STRIDE4)];
        buf[b * STRIDE4 + r * 2 + 0] = make_float4(P[0], P[1], P[2], P[3]);
        buf[b * STRIDE4 + r * 2 + 1] = make_float4(P[4], P[5], P[6], P[7]);
        __syncthreads();

        // ---- stage 2: O[v] = 128 + sum_x mu[x] * P[x][v] (broadcast reads) ----
        float O[8] = {128.f, 128.f, 128.f, 128.f, 128.f, 128.f, 128.f, 128.f};
#pragma unroll
        for (int x = 0; x < 8; ++x) {
            const float4 plo = buf[b * STRIDE4 + x * 2 + 0];
            const float4 phi = buf[b * STRIDE4 + x * 2 + 1];
            const float m = mu[x];
            O[0] = fmaf(m, plo.x, O[0]);
            O[1] = fmaf(m, plo.y, O[1]);
            O[2] = fmaf(m, plo.z, O[2]);
            O[3] = fmaf(m, plo.w, O[3]);
            O[4] = fmaf(m, phi.x, O[4]);
            O[5] = fmaf(m, phi.y, O[5]);
            O[6] = fmaf(m, phi.z, O[6]);
            O[7] = fmaf(m, phi.w, O[7]);
        }

        // ---- store my output row (coalesced; NT: don't pollute L3) ----
        if (tile * BPW + b < nblocks) {
            const size_t p = (size_t)tile * (BPW * 16) + 2 * t;
            fx4 v0 = {O[0], O[1], O[2], O[3]};
            fx4 v1 = {O[4], O[5], O[6], O[7]};
            __builtin_nontemporal_store(v0, &o4[p]);
            __builtin_nontemporal_store(v1, &o4[p + 1]);
        }

        clo = nlo; chi = nhi;
        tile = nxt;
        bufsel ^= 1;
    }
}

extern "C" void kernel_launch(void* const* d_in, const int* in_sizes, int n_in,
                              void* d_out, int out_size, void* d_ws, size_t ws_size,
                              hipStream_t stream) {
    const float* image = (const float*)d_in[0];
    const float* alpha = (const float*)d_in[1];
    const float* dct   = (const float*)d_in[2];
    float* outp = (float*)d_out;

    const int nblocks = in_sizes[0] / 64;
    const long long ntiles = ((long long)nblocks + BPW - 1) / BPW;
    int grid = (int)((ntiles < MAXWG) ? ntiles : MAXWG);
    if (grid < 1) grid = 1;

    dct8x8_kernel<<<grid, WG, 0, stream>>>(image, alpha, dct, outp, nblocks);
}

// Round 7
// 214.007 us; speedup vs baseline: 2.2350x; 2.2350x over previous
//
#include <hip/hip_runtime.h>

// Batched 8x8 iDCT: out = M^T * img * M + 128
//   M[i][j] = 0.5 * a[i] * cos((2j+1)*i*pi/16)
//   a[i]    = alpha[i*8+1]       (alpha = outer(a,a), a[1]==1)
//   cos term = dct[i*512 + j*8]  (dct_tensor[i,0,j,0]; cos(0)==1)
//
// Design G: row-per-lane, 2 blocks per thread, LDS only for the P-exchange.
//   - lane owns one row of each of its 2 blocks; loads/stores are 2x dwordx4
//     per block, lanes stride 32B -> coalesced 2KB/wave-instruction-pair
//   - all 4 loads issued up front -> 2x MLP of the R4 design, half the WG churn
//   - M broadcast to SGPRs via v_readlane (no scalar-FP on CDNA) -> low VGPR
//   - P staged in LDS, stride 17 float4/block -> bank-conflict-free writes and
//     8-lane-broadcast reads covering all 32 banks evenly
//   - two P buffers, ONE barrier per WG; plain stores (NT proven harmful in R6:
//     FETCH 996MB, WRITE 640MB vs 320/524 without)

#define WG      256
#define BPW     (WG / 8)            // 32 blocks per set
#define SETS    2                   // blocks per thread
#define BLKWG   (SETS * BPW)        // 64 blocks per WG
#define STRIDE4 17                  // float4 stride per block in LDS

__global__ __launch_bounds__(WG, 8) void dct8x8_kernel(
    const float* __restrict__ image,
    const float* __restrict__ alpha,
    const float* __restrict__ dct,
    float* __restrict__ out,
    int nblocks)
{
    __shared__ float4 lds4[SETS * BPW * STRIDE4];   // 2 x 8704B = 17408B

    const int t = threadIdx.x;
    const int b = t >> 3;          // local block 0..31 (within a set)
    const int r = t & 7;           // my row
    const int lane = t & 63;

    // ---- M -> SGPRs: one element per lane, readlane-broadcast ----
    float mv;
    {
        const int i = lane >> 3, j = lane & 7;
        mv = 0.5f * alpha[i * 8 + 1] * dct[i * 512 + j * 8];
    }
    float M[64];
#pragma unroll
    for (int k = 0; k < 64; ++k)
        M[k] = __int_as_float(__builtin_amdgcn_readlane(__float_as_int(mv), k));

    // ---- stage-2 weights M[x][r] (runtime r): per-lane loads, L1-hit ----
    float mu[8];
#pragma unroll
    for (int x = 0; x < 8; ++x)
        mu[x] = 0.5f * alpha[x * 8 + 1] * dct[x * 512 + r * 8];

    const float4* __restrict__ in4 = (const float4*)image;
    float4* __restrict__ o4 = (float4*)out;

    const long long wgbase = (long long)blockIdx.x * BLKWG;

    // ---- issue ALL loads up front (4 dwordx4 in flight per thread) ----
    float4 lo[SETS], hi[SETS];
#pragma unroll
    for (int s = 0; s < SETS; ++s) {
        const long long gblk = wgbase + s * BPW + b;
        if (gblk < nblocks) {
            const size_t p = (size_t)gblk * 16 + r * 2;
            lo[s] = in4[p];
            hi[s] = in4[p + 1];
        } else {
            lo[s] = make_float4(0.f, 0.f, 0.f, 0.f);
            hi[s] = lo[s];
        }
    }

    // ---- stage 1 per set: P[v] = sum_y row[y]*M[y][v]; stage to LDS ----
#pragma unroll
    for (int s = 0; s < SETS; ++s) {
        const float row[8] = {lo[s].x, lo[s].y, lo[s].z, lo[s].w,
                              hi[s].x, hi[s].y, hi[s].z, hi[s].w};
        float P[8];
#pragma unroll
        for (int v = 0; v < 8; ++v) {
            float acc = 0.0f;
#pragma unroll
            for (int y = 0; y < 8; ++y)
                acc = fmaf(row[y], M[y * 8 + v], acc);
            P[v] = acc;
        }
        float4* buf = &lds4[s * (BPW * STRIDE4)];
        buf[b * STRIDE4 + r * 2 + 0] = make_float4(P[0], P[1], P[2], P[3]);
        buf[b * STRIDE4 + r * 2 + 1] = make_float4(P[4], P[5], P[6], P[7]);
    }
    __syncthreads();

    // ---- stage 2 per set: O[v] = 128 + sum_x mu[x]*P[x][v]; store row ----
#pragma unroll
    for (int s = 0; s < SETS; ++s) {
        const float4* buf = &lds4[s * (BPW * STRIDE4)];
        float O[8] = {128.f, 128.f, 128.f, 128.f, 128.f, 128.f, 128.f, 128.f};
#pragma unroll
        for (int x = 0; x < 8; ++x) {
            const float4 plo = buf[b * STRIDE4 + x * 2 + 0];
            const float4 phi = buf[b * STRIDE4 + x * 2 + 1];
            const float m = mu[x];
            O[0] = fmaf(m, plo.x, O[0]);
            O[1] = fmaf(m, plo.y, O[1]);
            O[2] = fmaf(m, plo.z, O[2]);
            O[3] = fmaf(m, plo.w, O[3]);
            O[4] = fmaf(m, phi.x, O[4]);
            O[5] = fmaf(m, phi.y, O[5]);
            O[6] = fmaf(m, phi.z, O[6]);
            O[7] = fmaf(m, phi.w, O[7]);
        }
        const long long gblk = wgbase + s * BPW + b;
        if (gblk < nblocks) {
            const size_t p = (size_t)gblk * 16 + r * 2;
            o4[p]     = make_float4(O[0], O[1], O[2], O[3]);
            o4[p + 1] = make_float4(O[4], O[5], O[6], O[7]);
        }
    }
}

extern "C" void kernel_launch(void* const* d_in, const int* in_sizes, int n_in,
                              void* d_out, int out_size, void* d_ws, size_t ws_size,
                              hipStream_t stream) {
    const float* image = (const float*)d_in[0];
    const float* alpha = (const float*)d_in[1];
    const float* dct   = (const float*)d_in[2];
    float* outp = (float*)d_out;

    const int nblocks = in_sizes[0] / 64;
    const long long wgs = ((long long)nblocks + BLKWG - 1) / BLKWG;

    dct8x8_kernel<<<(int)wgs, WG, 0, stream>>>(image, alpha, dct, outp, nblocks);
}